// Round 3
// baseline (262.512 us; speedup 1.0000x reference)
//
#include <hip/hip_runtime.h>

#define NP 128

// 32 lanes per ray, 4 samples per lane (float4, 16B = coalescing sweet spot).
// Each wave handles 2 independent rays (2x ILP on the shuffle chains).
// Exclusive cumprod = per-lane quad product + 5-step shfl_up scan (width 32).
__global__ __launch_bounds__(256) void calc_ray_color_kernel(
    const float* __restrict__ rgb,      // [3, NR, NP]
    const float* __restrict__ density,  // [NR, NP]
    const float* __restrict__ dists,    // [NR, NP]
    const float* __restrict__ zvals,    // [NR, NP]
    float* __restrict__ out,            // rgb_res[3*NR] | bg[NR] | depth[NR] | weight[NR*NP]
    int NR)
{
    const int lane = threadIdx.x & 63;
    const int sub  = lane & 31;                  // lane within ray
    const int ray  = (blockIdx.x << 3) + ((threadIdx.x >> 6) << 1) + (lane >> 5);
    if (ray >= NR) return;

    const size_t base = (size_t)ray * NP + 4 * sub;
    const size_t cstride = (size_t)NR * NP;

    // Issue all 6 independent 16B loads up front for MLP.
    float4 den = *(const float4*)(density + base);
    float4 dst = *(const float4*)(dists + base);
    float4 z   = *(const float4*)(zvals + base);
    float4 c0  = *(const float4*)(rgb + base);
    float4 c1  = *(const float4*)(rgb + cstride + base);
    float4 c2  = *(const float4*)(rgb + 2 * cstride + base);

    float a0 = 1.0f - __expf(-den.x * dst.x);
    float a1 = 1.0f - __expf(-den.y * dst.y);
    float a2 = 1.0f - __expf(-den.z * dst.z);
    float a3 = 1.0f - __expf(-den.w * dst.w);
    float x0 = 1.0f - a0 + 1e-10f;
    float x1 = 1.0f - a1 + 1e-10f;
    float x2 = 1.0f - a2 + 1e-10f;
    float x3 = 1.0f - a3 + 1e-10f;

    // inclusive prefix product of per-lane quad products within 32-lane segment
    float p = (x0 * x1) * (x2 * x3);
    #pragma unroll
    for (int off = 1; off < 32; off <<= 1) {
        float v = __shfl_up(p, off, 32);
        if (sub >= off) p *= v;
    }
    // exclusive
    float excl = __shfl_up(p, 1, 32);
    if (sub == 0) excl = 1.0f;

    const float t0 = excl;
    const float t1 = t0 * x0;
    const float t2 = t1 * x1;
    const float t3 = t2 * x2;
    const float w0 = a0 * t0;
    const float w1 = a1 * t1;
    const float w2 = a2 * t2;
    const float w3 = a3 * t3;

    // weight out (after the 5*NR scalar outputs)
    *(float4*)(out + (size_t)5 * NR + base) = make_float4(w0, w1, w2, w3);

    float s0   = w0 * c0.x + w1 * c0.y + w2 * c0.z + w3 * c0.w;
    float s1   = w0 * c1.x + w1 * c1.y + w2 * c1.z + w3 * c1.w;
    float s2   = w0 * c2.x + w1 * c2.y + w2 * c2.z + w3 * c2.w;
    float sdep = w0 * z.x  + w1 * z.y  + w2 * z.z  + w3 * z.w;
    float sacc = (w0 + w1) + (w2 + w3);

    // 5-step reductions within 32-lane segment (independent chains pipeline)
    #pragma unroll
    for (int off = 16; off >= 1; off >>= 1) {
        s0   += __shfl_down(s0, off, 32);
        s1   += __shfl_down(s1, off, 32);
        s2   += __shfl_down(s2, off, 32);
        sdep += __shfl_down(sdep, off, 32);
        sacc += __shfl_down(sacc, off, 32);
    }

    if (sub == 0) {
        out[ray]                  = s0;
        out[(size_t)NR + ray]     = s1;
        out[2 * (size_t)NR + ray] = s2;
        out[3 * (size_t)NR + ray] = 1.0f - sacc;
        out[4 * (size_t)NR + ray] = sdep;
    }
}

extern "C" void kernel_launch(void* const* d_in, const int* in_sizes, int n_in,
                              void* d_out, int out_size, void* d_ws, size_t ws_size,
                              hipStream_t stream) {
    // d_in[0] = fg_vps  (UNUSED by reference — do not read)
    const float* rgb     = (const float*)d_in[1];
    const float* density = (const float*)d_in[2];
    const float* dists   = (const float*)d_in[3];
    const float* zvals   = (const float*)d_in[4];
    float* out = (float*)d_out;

    const int NR = in_sizes[2] / NP;   // density is [1,1,NR,NP]
    const int rays_per_block = 8;      // 4 waves * 2 rays/wave
    const int grid = (NR + rays_per_block - 1) / rays_per_block;

    calc_ray_color_kernel<<<grid, 256, 0, stream>>>(rgb, density, dists, zvals, out, NR);
}